// Round 1
// baseline (29.623 us; speedup 1.0000x reference)
//
#include <hip/hip_runtime.h>

#define NB   8
#define CIN  3
#define HIN  128
#define WIN  128
#define OC   32
#define KH   3
#define KW   3
#define HO   126
#define WO   126
#define KTOT 27          // CIN*KH*KW
#define TOTAL (NB*OC*HO*WO)

// Soft MAJ3 in bipolar form: with a=(x+1)/2 etc.,
// 2*(ab+ac+bc-2abc)-1  ==  (x + y + z - x*y*z) / 2   (exact algebra)
__device__ __forceinline__ float maj3(float a, float b, float c) {
    return 0.5f * (a + b + c - a * b * c);
}

__global__ __launch_bounds__(256)
void sconv2d_maj3_kernel(const float* __restrict__ x,
                         const float* __restrict__ w,
                         float* __restrict__ out) {
    __shared__ float ws[OC * KTOT];           // 3456 B
    for (int i = threadIdx.x; i < OC * KTOT; i += blockDim.x)
        ws[i] = w[i];
    __syncthreads();

    int idx = blockIdx.x * blockDim.x + threadIdx.x;
    if (idx >= TOTAL) return;

    // idx = ((n*OC + oc)*HO + ho)*WO + wo   (matches reference output layout)
    int wo = idx % WO;
    int t  = idx / WO;
    int ho = t % HO;  t /= HO;
    int oc = t % OC;
    int n  = t / OC;

    const float* wb = &ws[oc * KTOT];         // wave-uniform -> LDS broadcast

    float lvl1[9];
    #pragma unroll
    for (int c = 0; c < CIN; ++c) {
        #pragma unroll
        for (int kh = 0; kh < KH; ++kh) {
            const float* xr = x + (((n * CIN + c) * HIN) + (ho + kh)) * WIN + wo;
            // k-order is channel-major: k = c*9 + kh*3 + kw; level-1 groups are
            // consecutive triples, i.e. fixed (c,kh), kw=0..2.
            float p0 = xr[0] * wb[c * 9 + kh * 3 + 0];
            float p1 = xr[1] * wb[c * 9 + kh * 3 + 1];
            float p2 = xr[2] * wb[c * 9 + kh * 3 + 2];
            lvl1[c * 3 + kh] = maj3(p0, p1, p2);
        }
    }
    float m0 = maj3(lvl1[0], lvl1[1], lvl1[2]);
    float m1 = maj3(lvl1[3], lvl1[4], lvl1[5]);
    float m2 = maj3(lvl1[6], lvl1[7], lvl1[8]);
    out[idx] = maj3(m0, m1, m2);
}

extern "C" void kernel_launch(void* const* d_in, const int* in_sizes, int n_in,
                              void* d_out, int out_size, void* d_ws, size_t ws_size,
                              hipStream_t stream) {
    const float* x = (const float*)d_in[0];
    const float* w = (const float*)d_in[1];
    float* out     = (float*)d_out;
    int grid = (TOTAL + 255) / 256;
    sconv2d_maj3_kernel<<<grid, 256, 0, stream>>>(x, w, out);
}

// Round 3
// 19.733 us; speedup vs baseline: 1.5012x; 1.5012x over previous
//
#include <hip/hip_runtime.h>

#define NB   8
#define CIN  3
#define HIN  128
#define WIN  128
#define OC   32
#define HO   126
#define WO   126
#define SPATIAL (NB*HO*WO)     // 127008
#define KTOT 27
#define PACK 36                // 27 halved weights + 9 halved group triple-products
#define OCPB 8                 // oc values per thread (chunk indexed by blockIdx.y)

// maj3 bipolar: 0.5*(a+b+c - a*b*c)
__device__ __forceinline__ float maj3(float a, float b, float c) {
    float s = a + b + c;
    float t = a * b;
    return 0.5f * fmaf(-t, c, s);
}

// Pre-pack per-oc weights: [0..26] = 0.5*w_k (natural k order, groups = consecutive
// triples), [27..35] = 0.5 * w_{3g} * w_{3g+1} * w_{3g+2}.
__global__ __launch_bounds__(128)
void prepack_kernel(const float* __restrict__ w, float* __restrict__ packed) {
    int i = blockIdx.x * 128 + threadIdx.x;
    if (i >= OC * PACK) return;
    int oc = i / PACK, s = i % PACK;
    const float* wp = w + oc * KTOT;
    float v;
    if (s < KTOT) {
        v = 0.5f * wp[s];
    } else {
        int g = s - KTOT;
        v = 0.5f * wp[3 * g] * wp[3 * g + 1] * wp[3 * g + 2];
    }
    packed[i] = v;
}

__global__ __launch_bounds__(256)
void sconv2d_kernel(const float* __restrict__ x,
                    const float* __restrict__ packed,
                    float* __restrict__ out) {
    __shared__ __align__(16) float ws[OCPB * PACK];   // 288 floats = 1152 B
    for (int i = threadIdx.x; i < OCPB * PACK; i += 256)   // FIX: 288 > blockDim
        ws[i] = packed[blockIdx.y * (OCPB * PACK) + i];
    __syncthreads();

    int pos = blockIdx.x * 256 + threadIdx.x;
    if (pos >= SPATIAL) return;
    int wo = pos % WO;
    int t  = pos / WO;
    int ho = t % HO;
    int n  = t / HO;

    // Load the 27-value patch once; compute oc-independent triple products.
    float xv[KTOT];
    float Xg[9];
    #pragma unroll
    for (int r = 0; r < 9; ++r) {          // r = c*3 + kh
        int c = r / 3, kh = r % 3;
        const float* xr = x + (((n * CIN + c) * HIN) + ho + kh) * WIN + wo;
        float a = xr[0], b = xr[1], d = xr[2];
        xv[3 * r]     = a;
        xv[3 * r + 1] = b;
        xv[3 * r + 2] = d;
        Xg[r] = a * b * d;
    }

    size_t obase = ((size_t)(n * OC) * HO + ho) * WO + wo;

    #pragma unroll
    for (int i = 0; i < OCPB; ++i) {
        // wave-uniform LDS reads -> broadcast; 144 B per oc block, 16 B aligned
        const float4* wv = (const float4*)&ws[i * PACK];
        float ww[PACK];
        #pragma unroll
        for (int j = 0; j < 9; ++j)
            ((float4*)ww)[j] = wv[j];

        float l1[9];
        #pragma unroll
        for (int g = 0; g < 9; ++g) {
            // lvl1 = 0.5*sum(x*w) - 0.5*X*W  (exact refactor of soft-MAJ3)
            float s = fmaf(xv[3 * g], ww[3 * g],
                      fmaf(xv[3 * g + 1], ww[3 * g + 1],
                           xv[3 * g + 2] * ww[3 * g + 2]));
            l1[g] = fmaf(-Xg[g], ww[KTOT + g], s);
        }
        float m0 = maj3(l1[0], l1[1], l1[2]);
        float m1 = maj3(l1[3], l1[4], l1[5]);
        float m2 = maj3(l1[6], l1[7], l1[8]);

        int oc = blockIdx.y * OCPB + i;
        out[obase + (size_t)oc * (HO * WO)] = maj3(m0, m1, m2);
    }
}

extern "C" void kernel_launch(void* const* d_in, const int* in_sizes, int n_in,
                              void* d_out, int out_size, void* d_ws, size_t ws_size,
                              hipStream_t stream) {
    const float* x = (const float*)d_in[0];
    const float* w = (const float*)d_in[1];
    float* out     = (float*)d_out;
    float* packed  = (float*)d_ws;   // 1152 floats

    prepack_kernel<<<dim3((OC * PACK + 127) / 128), 128, 0, stream>>>(w, packed);

    dim3 grid((SPATIAL + 255) / 256, OC / OCPB);
    sconv2d_kernel<<<grid, 256, 0, stream>>>(x, packed, out);
}

// Round 4
// 14.819 us; speedup vs baseline: 1.9990x; 1.3316x over previous
//
#include <hip/hip_runtime.h>

typedef float float2v __attribute__((ext_vector_type(2)));

#define NB   8
#define CIN  3
#define HIN  128
#define WIN  128
#define OC   32
#define HO   126
#define WO   126
#define PAIRS (NB*HO*(WO/2))   // 63504 position-pairs (2 adjacent wo per thread)
#define KTOT 27
#define PACK 36                // 9 groups x {w0/2, w1/2, w2/2, (w0*w1*w2)/2}
#define OCPB 8                 // ocs per block (blockIdx.y selects chunk of 8)

__device__ __forceinline__ float2v splat(float s) { return (float2v){s, s}; }

// bipolar soft-MAJ3: (a+b+c - a*b*c)/2, vectorized over 2 positions
__device__ __forceinline__ float2v maj3v(float2v a, float2v b, float2v c) {
    float2v s = a + b + c;
    float2v t = a * b;
    return 0.5f * __builtin_elementwise_fma(-t, c, s);
}

__global__ __launch_bounds__(256)
void sconv2d_kernel(const float* __restrict__ x,
                    const float* __restrict__ w,
                    float* __restrict__ out) {
    // Per-block packed weights for this block's 8 ocs. Layout: [oc][group] ->
    // float4 {0.5*w(3g), 0.5*w(3g+1), 0.5*w(3g+2), 0.5*w(3g)*w(3g+1)*w(3g+2)}
    __shared__ __align__(16) float ws[OCPB * PACK];   // 1152 B
    {
        int ocbase = blockIdx.y * OCPB;
        for (int i = threadIdx.x; i < OCPB * PACK; i += 256) {
            int oc = i / PACK, r = i % PACK;
            int g = r / 4, j = r % 4;
            const float* wp = w + (ocbase + oc) * KTOT + 3 * g;
            float v = (j < 3) ? 0.5f * wp[j]
                              : 0.5f * wp[0] * wp[1] * wp[2];
            ws[i] = v;
        }
    }
    __syncthreads();

    int pp = blockIdx.x * 256 + threadIdx.x;
    if (pp >= PAIRS) return;
    int w2  = pp % (WO / 2);
    int t   = pp / (WO / 2);
    int ho  = t % HO;
    int n   = t / HO;
    int wo0 = 2 * w2;

    // Load the 2-position patch (9 rows x 4 floats) once; build pk pairs and
    // the oc-independent triple products Xg = {x0*x1*x2, x1*x2*x3}.
    float2v Av[9], Bv[9], Cv[9], Xg[9];
    #pragma unroll
    for (int r = 0; r < 9; ++r) {          // r = c*3 + kh
        int c = r / 3, kh = r % 3;
        const float* xr = x + (((n * CIN + c) * HIN) + ho + kh) * WIN + wo0;
        float2v P0 = *(const float2v*)xr;        // 8B aligned (wo0 even)
        float2v P1 = *(const float2v*)(xr + 2);
        float2v B;
        B.x = P0.y; B.y = P1.x;
        Av[r] = P0;
        Bv[r] = B;
        Cv[r] = P1;
        Xg[r] = P0 * B * P1;
    }

    size_t obase = ((size_t)(n * OC) * HO + ho) * WO + wo0;
    const size_t ocstride = (size_t)HO * WO;

    #pragma unroll
    for (int i = 0; i < OCPB; ++i) {
        const float4* wg = (const float4*)&ws[i * PACK];  // wave-uniform -> broadcast
        float2v l1[9];
        #pragma unroll
        for (int g = 0; g < 9; ++g) {
            float4 q = wg[g];                // one ds_read_b128
            // l1 = 0.5*(x.w) - 0.5*Xg*W   (exact refactor of soft-MAJ3)
            float2v s = __builtin_elementwise_fma(Av[g], splat(q.x),
                        __builtin_elementwise_fma(Bv[g], splat(q.y),
                                                  Cv[g] * splat(q.z)));
            l1[g] = __builtin_elementwise_fma(-Xg[g], splat(q.w), s);
        }
        float2v m0 = maj3v(l1[0], l1[1], l1[2]);
        float2v m1 = maj3v(l1[3], l1[4], l1[5]);
        float2v m2 = maj3v(l1[6], l1[7], l1[8]);
        float2v res = maj3v(m0, m1, m2);

        int oc = blockIdx.y * OCPB + i;
        *(float2v*)(out + obase + (size_t)oc * ocstride) = res;  // dwordx2 store
    }
}

extern "C" void kernel_launch(void* const* d_in, const int* in_sizes, int n_in,
                              void* d_out, int out_size, void* d_ws, size_t ws_size,
                              hipStream_t stream) {
    const float* x = (const float*)d_in[0];
    const float* w = (const float*)d_in[1];
    float* out     = (float*)d_out;

    dim3 grid((PAIRS + 255) / 256, OC / OCPB);
    sconv2d_kernel<<<grid, 256, 0, stream>>>(x, w, out);
}

// Round 6
// 14.283 us; speedup vs baseline: 2.0739x; 1.0375x over previous
//
#include <hip/hip_runtime.h>

typedef float float2v __attribute__((ext_vector_type(2)));

#define NB   8
#define CIN  3
#define HIN  128
#define WIN  128
#define OC   32
#define HO   126
#define WO   126
#define PAIRS (NB*HO*(WO/2))   // 63504 position-pairs (2 adjacent wo per thread)
#define KTOT 27
#define PACK 36                // 9 groups x {w0/2, w1/2, w2/2, (w0*w1*w2)/2}
#define OCPB 8                 // ocs per block (blockIdx.y selects chunk of 8)
#define OCSTRIDE (HO*WO)       // 15876

__device__ __forceinline__ float2v splat(float s) { return (float2v){s, s}; }

// bipolar soft-MAJ3: (a+b+c - a*b*c)/2, vectorized over 2 positions
__device__ __forceinline__ float2v maj3v(float2v a, float2v b, float2v c) {
    float2v s = a + b + c;
    float2v t = a * b;
    return 0.5f * __builtin_elementwise_fma(-t, c, s);
}

__global__ __launch_bounds__(256, 4)   // cap VGPR<=128 -> 4 waves/SIMD resident
void sconv2d_kernel(const float* __restrict__ x,
                    const float* __restrict__ w,
                    float* __restrict__ out) {
    // Per-block packed weights for this block's 8 ocs. Layout: [oc][group] ->
    // float4 {0.5*w(3g), 0.5*w(3g+1), 0.5*w(3g+2), 0.5*w(3g)*w(3g+1)*w(3g+2)}
    __shared__ __align__(16) float ws[OCPB * PACK];   // 1152 B
    {
        int ocbase = blockIdx.y * OCPB;
        for (int i = threadIdx.x; i < OCPB * PACK; i += 256) {
            int oc = i / PACK, r = i % PACK;
            int g = r / 4, j = r % 4;
            const float* wp = w + (ocbase + oc) * KTOT + 3 * g;
            float v = (j < 3) ? 0.5f * wp[j]
                              : 0.5f * wp[0] * wp[1] * wp[2];
            ws[i] = v;
        }
    }
    __syncthreads();

    int pp = blockIdx.x * 256 + threadIdx.x;
    if (pp >= PAIRS) return;
    int w2  = pp % (WO / 2);
    int t   = pp / (WO / 2);
    int ho  = t % HO;
    int n   = t / HO;
    int wo0 = 2 * w2;

    // Load the 2-position patch (9 rows x 4 floats) once; build pk pairs and
    // the oc-independent triple products Xg = {x0*x1*x2, x1*x2*x3}.
    float2v Av[9], Bv[9], Cv[9], Xg[9];
    #pragma unroll
    for (int r = 0; r < 9; ++r) {          // r = c*3 + kh
        int c = r / 3, kh = r % 3;
        const float* xr = x + (((n * CIN + c) * HIN) + ho + kh) * WIN + wo0;
        float2v P0 = *(const float2v*)xr;        // 8B aligned (wo0 even)
        float2v P1 = *(const float2v*)(xr + 2);
        float2v B  = __builtin_shufflevector(P0, P1, 1, 2);
        Av[r] = P0;
        Bv[r] = B;
        Cv[r] = P1;
        Xg[r] = P0 * B * P1;
    }

    // FIX(R5): include this block's oc-chunk base in the output offset.
    int obase = ((n * OC + blockIdx.y * OCPB) * HO + ho) * WO + wo0;  // int32-safe (<4.1M)

    #pragma unroll 2                     // bound live ranges (VGPR<=128)
    for (int i = 0; i < OCPB; ++i) {
        const float4* wg = (const float4*)&ws[i * PACK];  // wave-uniform -> broadcast
        float2v l1[9];
        #pragma unroll
        for (int g = 0; g < 9; ++g) {
            float4 q = wg[g];                // one ds_read_b128
            // l1 = 0.5*(x.w) - 0.5*Xg*W   (exact refactor of soft-MAJ3)
            float2v s = __builtin_elementwise_fma(Av[g], splat(q.x),
                        __builtin_elementwise_fma(Bv[g], splat(q.y),
                                                  Cv[g] * splat(q.z)));
            l1[g] = __builtin_elementwise_fma(-Xg[g], splat(q.w), s);
        }
        float2v m0 = maj3v(l1[0], l1[1], l1[2]);
        float2v m1 = maj3v(l1[3], l1[4], l1[5]);
        float2v m2 = maj3v(l1[6], l1[7], l1[8]);
        float2v res = maj3v(m0, m1, m2);

        // write-once streaming output: nontemporal dwordx2 store
        __builtin_nontemporal_store(res, (float2v*)(out + obase + i * OCSTRIDE));
    }
}

extern "C" void kernel_launch(void* const* d_in, const int* in_sizes, int n_in,
                              void* d_out, int out_size, void* d_ws, size_t ws_size,
                              hipStream_t stream) {
    const float* x = (const float*)d_in[0];
    const float* w = (const float*)d_in[1];
    float* out     = (float*)d_out;

    dim3 grid((PAIRS + 255) / 256, OC / OCPB);
    sconv2d_kernel<<<grid, 256, 0, stream>>>(x, w, out);
}